// Round 5
// baseline (173.160 us; speedup 1.0000x reference)
//
#include <hip/hip_runtime.h>
#include <math.h>

#define KSEL 15
#define CIN 128
#define CF 16
#define HH 112
#define PLANE 12544      // 112*112
#define NN 256
#define ROWSTRIDE 20     // padded feature row (18 used)
#define KVSTRIDE 260     // key-array row stride (bank-safe, 16B-aligned)

static __device__ __forceinline__ unsigned mono32(float f) {
    unsigned u = __float_as_uint(f);
    return ((int)u < 0) ? ~u : (u | 0x80000000u);
}
static __device__ __forceinline__ float demono32(unsigned u) {
    return ((int)u < 0) ? __uint_as_float(u & 0x7FFFFFFFu) : __uint_as_float(~u);
}

// ---------------- K1: features (fp64 conv -> augment -> normalize) ----------------
__global__ __launch_bounds__(256) void k1_features(
    const float* __restrict__ x, const float* __restrict__ fw, const float* __restrict__ fb,
    double* __restrict__ xa64, float* __restrict__ xa32, unsigned* __restrict__ dirtyCount)
{
    __shared__ float lfw[CIN * CF];   // [c][d]
    __shared__ float lfb[CF];
    const int tid = threadIdx.x;
    if (blockIdx.x == 0 && tid == 0) *dirtyCount = 0u;
    const int p  = blockIdx.x >> 2;
    const int n0 = (blockIdx.x & 3) * 64;
    const int b = p / 49, g = p % 49;
    const int gI = g / 7, gJ = g % 7;
    const float* xb = x + (size_t)b * CIN * PLANE + (size_t)(gI * 16 * HH + gJ * 16);

    for (int q = tid; q < CIN * CF; q += 256) { int d = q >> 7, c = q & 127; lfw[c * CF + d] = fw[q]; }
    if (tid < CF) lfb[tid] = fb[tid];
    __syncthreads();

    const int nl = tid >> 2, dq = tid & 3;
    const int n = n0 + nl, i = n >> 4, j = n & 15;
    const float* xp = xb + i * HH + j;

    // two accumulator sets (even/odd c) to halve the fp64 FMA dependency chain
    double e0 = 0.0, e1 = 0.0, e2 = 0.0, e3 = 0.0;
    double o0 = 0.0, o1 = 0.0, o2 = 0.0, o3 = 0.0;
#pragma unroll 2
    for (int c = 0; c < CIN; c += 2) {
        double xc0 = (double)xp[(size_t)c * PLANE];
        double xc1 = (double)xp[(size_t)(c + 1) * PLANE];
        float4 wv0 = *(const float4*)&lfw[c * CF + dq * 4];
        float4 wv1 = *(const float4*)&lfw[(c + 1) * CF + dq * 4];
        e0 = fma(xc0, (double)wv0.x, e0);
        e1 = fma(xc0, (double)wv0.y, e1);
        e2 = fma(xc0, (double)wv0.z, e2);
        e3 = fma(xc0, (double)wv0.w, e3);
        o0 = fma(xc1, (double)wv1.x, o0);
        o1 = fma(xc1, (double)wv1.y, o1);
        o2 = fma(xc1, (double)wv1.z, o2);
        o3 = fma(xc1, (double)wv1.w, o3);
    }
    double a0 = e0 + o0 + (double)lfb[dq * 4 + 0];
    double a1 = e1 + o1 + (double)lfb[dq * 4 + 1];
    double a2 = e2 + o2 + (double)lfb[dq * 4 + 2];
    double a3 = e3 + o3 + (double)lfb[dq * 4 + 3];

    const double GDIV = 4.618802153517006 + 1e-5;
    double gx = ((double)i - 7.5) / GDIV;
    double gy = ((double)j - 7.5) / GDIV;

    double ss = a0 * a0;
    ss = fma(a1, a1, ss); ss = fma(a2, a2, ss); ss = fma(a3, a3, ss);
    if (dq == 3) { ss = fma(gx, gx, ss); ss = fma(gy, gy, ss); }
    ss += __shfl_xor(ss, 1);
    ss += __shfl_xor(ss, 2);
    double nrm = fmax(sqrt(ss), 1e-8);

    size_t ro = ((size_t)p * NN + n) * ROWSTRIDE;
    double f0 = a0 / nrm, f1 = a1 / nrm, f2 = a2 / nrm, f3 = a3 / nrm;
    xa64[ro + dq * 4 + 0] = f0; xa64[ro + dq * 4 + 1] = f1;
    xa64[ro + dq * 4 + 2] = f2; xa64[ro + dq * 4 + 3] = f3;
    xa32[ro + dq * 4 + 0] = (float)f0; xa32[ro + dq * 4 + 1] = (float)f1;
    xa32[ro + dq * 4 + 2] = (float)f2; xa32[ro + dq * 4 + 3] = (float)f3;
    if (dq == 3) {
        double g0 = gx / nrm, g1 = gy / nrm;
        xa64[ro + 16] = g0; xa64[ro + 17] = g1; xa64[ro + 18] = 0.0; xa64[ro + 19] = 0.0;
        xa32[ro + 16] = (float)g0; xa32[ro + 17] = (float)g1; xa32[ro + 18] = 0.f; xa32[ro + 19] = 0.f;
    }
}

// ---------------- K2: 4x4-tiled fp32 sims -> LDS keys -> sort16+merge selection ----------------
__global__ __launch_bounds__(256) void k2_select(
    const float* __restrict__ xa32,
    const float* __restrict__ ea, const float* __restrict__ eb,
    int* __restrict__ topi, float* __restrict__ wkout,
    unsigned* __restrict__ dirtyCount, int* __restrict__ dirtyList)
{
    __shared__ float tile[NN * ROWSTRIDE];    // 20 KB
    __shared__ unsigned kv[16 * KVSTRIDE];    // 16.6 KB: per-row 256 packed keys
    const int tid = threadIdx.x;
    const int p = blockIdx.x >> 4, sub = blockIdx.x & 15;

    const float* src = xa32 + (size_t)p * NN * ROWSTRIDE;
#pragma unroll
    for (int q = 0; q < 5; ++q) {
        int idx = q * 256 + tid;
        ((float4*)tile)[idx] = ((const float4*)src)[idx];
    }
    __syncthreads();

    // ---- phase 1: sims, 4 rows (per wave) x 4 m (per lane) register tile ----
    const int w    = tid >> 6;         // wave 0..3
    const int lane = tid & 63;
    const int r0   = sub * 16 + w * 4; // 4 rows in patch
    const int m0   = lane * 4;         // 4 m columns

    float xr[4][18];
#pragma unroll
    for (int rr = 0; rr < 4; ++rr) {
        const float4* xp4 = (const float4*)&tile[(r0 + rr) * ROWSTRIDE];
        float4 x0 = xp4[0], x1 = xp4[1], x2 = xp4[2], x3 = xp4[3];
        float2 xt = *(const float2*)&tile[(r0 + rr) * ROWSTRIDE + 16];
        xr[rr][0]=x0.x; xr[rr][1]=x0.y; xr[rr][2]=x0.z; xr[rr][3]=x0.w;
        xr[rr][4]=x1.x; xr[rr][5]=x1.y; xr[rr][6]=x1.z; xr[rr][7]=x1.w;
        xr[rr][8]=x2.x; xr[rr][9]=x2.y; xr[rr][10]=x2.z; xr[rr][11]=x2.w;
        xr[rr][12]=x3.x; xr[rr][13]=x3.y; xr[rr][14]=x3.z; xr[rr][15]=x3.w;
        xr[rr][16]=xt.x; xr[rr][17]=xt.y;
    }

    unsigned keys[4][4];
#pragma unroll
    for (int mm = 0; mm < 4; ++mm) {
        const int m = m0 + mm;
        const float4* bp4 = (const float4*)&tile[m * ROWSTRIDE];
        float4 b0 = bp4[0], b1 = bp4[1], b2 = bp4[2], b3 = bp4[3];
        float2 bt = *(const float2*)&tile[m * ROWSTRIDE + 16];
#pragma unroll
        for (int rr = 0; rr < 4; ++rr) {
            float s = 0.f;
            s = fmaf(xr[rr][0],  b0.x, s); s = fmaf(xr[rr][1],  b0.y, s);
            s = fmaf(xr[rr][2],  b0.z, s); s = fmaf(xr[rr][3],  b0.w, s);
            s = fmaf(xr[rr][4],  b1.x, s); s = fmaf(xr[rr][5],  b1.y, s);
            s = fmaf(xr[rr][6],  b1.z, s); s = fmaf(xr[rr][7],  b1.w, s);
            s = fmaf(xr[rr][8],  b2.x, s); s = fmaf(xr[rr][9],  b2.y, s);
            s = fmaf(xr[rr][10], b2.z, s); s = fmaf(xr[rr][11], b2.w, s);
            s = fmaf(xr[rr][12], b3.x, s); s = fmaf(xr[rr][13], b3.y, s);
            s = fmaf(xr[rr][14], b3.z, s); s = fmaf(xr[rr][15], b3.w, s);
            s = fmaf(xr[rr][16], bt.x, s); s = fmaf(xr[rr][17], bt.y, s);
            keys[rr][mm] = (mono32(s) & 0xFFFFFF00u) | (unsigned)(255 - m);
        }
    }
#pragma unroll
    for (int rr = 0; rr < 4; ++rr) {
        uint4 kw = make_uint4(keys[rr][0], keys[rr][1], keys[rr][2], keys[rr][3]);
        *(uint4*)&kv[(w * 4 + rr) * KVSTRIDE + m0] = kw;
    }
    __syncthreads();

    // ---- phase 2: per-row top-16 selection (16 lanes per row) ----
    const int l16 = tid & 15;
    const int rb  = tid >> 4;            // row-in-block 0..15
    const int row = p * NN + sub * 16 + rb;

    unsigned k[16];
    {
        const uint4* kp = (const uint4*)&kv[rb * KVSTRIDE + l16 * 16];
        uint4 q0 = kp[0], q1 = kp[1], q2 = kp[2], q3 = kp[3];
        k[0]=q0.x; k[1]=q0.y; k[2]=q0.z; k[3]=q0.w;
        k[4]=q1.x; k[5]=q1.y; k[6]=q1.z; k[7]=q1.w;
        k[8]=q2.x; k[9]=q2.y; k[10]=q2.z; k[11]=q2.w;
        k[12]=q3.x; k[13]=q3.y; k[14]=q3.z; k[15]=q3.w;
    }

    // bitonic sort ascending (registers, fully unrolled)
#pragma unroll
    for (int kk = 2; kk <= 16; kk <<= 1) {
#pragma unroll
        for (int jj = kk >> 1; jj > 0; jj >>= 1) {
#pragma unroll
            for (int ii = 0; ii < 16; ++ii) {
                int ll = ii ^ jj;
                if (ll > ii) {
                    bool up = ((ii & kk) == 0);
                    unsigned a = k[ii], bbv = k[ll];
                    bool sw = up ? (a > bbv) : (a < bbv);
                    k[ii] = sw ? bbv : a; k[ll] = sw ? a : bbv;
                }
            }
        }
    }

    // 16-lane merge, spill-free: head indexed from registers via cndmask chain
    int ptr = 15;
    unsigned myhead = k[15];
    unsigned mycand = 0;
#pragma unroll
    for (int e = 0; e < 16; ++e) {
        unsigned W = myhead;
        unsigned o;
        o = __shfl_xor(W, 1);  W = (o > W) ? o : W;
        o = __shfl_xor(W, 2);  W = (o > W) ? o : W;
        o = __shfl_xor(W, 4);  W = (o > W) ? o : W;
        o = __shfl_xor(W, 8);  W = (o > W) ? o : W;
        if (l16 == e) mycand = W;
        bool won = (myhead == W);
        ptr -= won ? 1 : 0;
        int rp = ptr < 0 ? 0 : ptr;
        unsigned nh = k[0];
#pragma unroll
        for (int ii = 1; ii < 16; ++ii) nh = (rp == ii) ? k[ii] : nh;
        myhead = won ? nh : myhead;
    }

    // certification: fp64 top-15 set == fp32 top-15 set unless boundary gap too small
    unsigned v15 = __shfl(mycand, 14, 16);
    unsigned v16 = __shfl(mycand, 15, 16);
    float lo = demono32(v15 & 0xFFFFFF00u) - 1e-5f;
    float hi = demono32((v16 & 0xFFFFFF00u) + 0x100u) + 1e-5f;
    bool dirty = !(hi < lo);
    if (l16 == 0 && dirty) {
        unsigned slot = atomicAdd(dirtyCount, 1u);
        dirtyList[slot] = row;
    }

    // weights from fp32 sims (clean rows; dirty rows overwritten by K2b)
    int mym = 255 - (int)(mycand & 0xFFu);
    float sv = demono32(mycand & 0xFFFFFF00u);
    float alpha = ea[0], beta = eb[0];
    float sg = 1.f / (1.f + expf(-(beta + alpha * sv)));
    float v = (l16 < KSEL) ? sg : -1e30f;
    float mx = v, of;
    of = __shfl_xor(mx, 1); mx = fmaxf(mx, of);
    of = __shfl_xor(mx, 2); mx = fmaxf(mx, of);
    of = __shfl_xor(mx, 4); mx = fmaxf(mx, of);
    of = __shfl_xor(mx, 8); mx = fmaxf(mx, of);
    float ex = expf(v - mx);
    float sm = ex;
    of = __shfl_xor(sm, 1); sm += of;
    of = __shfl_xor(sm, 2); sm += of;
    of = __shfl_xor(sm, 4); sm += of;
    of = __shfl_xor(sm, 8); sm += of;

    topi[row * 16 + l16] = mym;
    wkout[row * 16 + l16] = (l16 < KSEL) ? (ex / sm) : 0.f;
}

// ---------------- K2b: exact fp64 redo for dirty rows (persistent, wave per row) ----------------
__global__ __launch_bounds__(64) void k2b_dirty(
    const double* __restrict__ xa64, const float* __restrict__ ea, const float* __restrict__ eb,
    const unsigned* __restrict__ dirtyCount, const int* __restrict__ dirtyList,
    int* __restrict__ topi, float* __restrict__ wkout)
{
    const int nd = (int)*dirtyCount;
    const int lane = threadIdx.x;
    for (int idx = blockIdx.x; idx < nd; idx += gridDim.x) {
        const int row = dirtyList[idx];
        const int p = row >> 8;
        const double* xr64 = xa64 + (size_t)row * ROWSTRIDE;

        double sv[4]; int smi[4];
#pragma unroll
        for (int s4 = 0; s4 < 4; ++s4) {
            int m = s4 * 64 + lane;
            const double* xm64 = xa64 + ((size_t)p * NN + m) * ROWSTRIDE;
            double s = 0.0;
#pragma unroll
            for (int d = 0; d < 18; ++d) s = fma(xr64[d], xm64[d], s);
            sv[s4] = s; smi[s4] = m;
        }

        double cv = -3.0; int cm = 0;
#pragma unroll
        for (int e = 0; e < KSEL; ++e) {
            double lv = sv[0]; int lm = smi[0];
#pragma unroll
            for (int s4 = 1; s4 < 4; ++s4) {
                bool t = (sv[s4] > lv) || (sv[s4] == lv && smi[s4] < lm);
                lv = t ? sv[s4] : lv; lm = t ? smi[s4] : lm;
            }
#pragma unroll
            for (int off = 1; off < 64; off <<= 1) {
                double ov = __shfl_xor(lv, off);
                int    om = __shfl_xor(lm, off);
                bool t = (ov > lv) || (ov == lv && om < lm);
                lv = t ? ov : lv; lm = t ? om : lm;
            }
            if (lane == e) { cv = lv; cm = lm; }
#pragma unroll
            for (int s4 = 0; s4 < 4; ++s4) if (smi[s4] == lm) sv[s4] = -3.0;
        }

        float alpha = ea[0], beta = eb[0];
        float sg = 1.f / (1.f + expf(-(beta + alpha * (float)cv)));
        float v = (lane < KSEL) ? sg : -1e30f;
        float mx = v, of;
        for (int off = 1; off < 64; off <<= 1) { of = __shfl_xor(mx, off); mx = fmaxf(mx, of); }
        float ex = expf(v - mx);
        float sm = ex;
        for (int off = 1; off < 64; off <<= 1) { of = __shfl_xor(sm, off); sm += of; }
        float w = ex / sm;
        if (lane < 16) {
            topi[row * 16 + lane] = (lane < KSEL) ? cm : 0;
            wkout[row * 16 + lane] = (lane < KSEL) ? w : 0.f;
        }
    }
}

// ---------------- K3: weighted gather-aggregate ----------------
__global__ __launch_bounds__(256) void k3_aggregate(
    const float* __restrict__ x, const int* __restrict__ topi, const float* __restrict__ wk,
    float* __restrict__ out)
{
    __shared__ float tile[NN * ROWSTRIDE];   // [pos][20], 16 channels used
    const int tid = threadIdx.x;
    const int pb = blockIdx.x >> 3, cg = blockIdx.x & 7, c0 = cg * 16;
    const int b = pb / 49, g = pb % 49;
    const int gI = g / 7, gJ = g % 7;
    const float* xb = x + ((size_t)b * CIN + c0) * PLANE + (size_t)(gI * 16 * HH + gJ * 16);

#pragma unroll
    for (int rep = 0; rep < 4; ++rep) {
        int linear = rep * 256 + tid;
        int cc = linear >> 6, chunk = linear & 63;
        int pos = chunk * 4, ii = pos >> 4, jj = pos & 15;
        float4 v = *(const float4*)(xb + (size_t)cc * PLANE + ii * HH + jj);
        tile[(pos + 0) * ROWSTRIDE + cc] = v.x;
        tile[(pos + 1) * ROWSTRIDE + cc] = v.y;
        tile[(pos + 2) * ROWSTRIDE + cc] = v.z;
        tile[(pos + 3) * ROWSTRIDE + cc] = v.w;
    }
    __syncthreads();

    const int n = tid;
    const int row = pb * NN + n;
    float acc[16];
#pragma unroll
    for (int c = 0; c < 16; ++c) acc[c] = 0.f;

#pragma unroll
    for (int kq = 0; kq < 4; ++kq) {
        int4   mi4 = ((const int4*)(topi + (size_t)row * 16))[kq];
        float4 w4  = ((const float4*)(wk  + (size_t)row * 16))[kq];
        const int   mis[4] = { mi4.x, mi4.y, mi4.z, mi4.w };
        const float ws4[4] = { w4.x, w4.y, w4.z, w4.w };
#pragma unroll
        for (int u = 0; u < 4; ++u) {
            float w = ws4[u];
            const float4* sp = (const float4*)&tile[mis[u] * ROWSTRIDE];
#pragma unroll
            for (int q = 0; q < 4; ++q) {
                float4 f = sp[q];
                acc[q * 4 + 0] = fmaf(w, f.x, acc[q * 4 + 0]);
                acc[q * 4 + 1] = fmaf(w, f.y, acc[q * 4 + 1]);
                acc[q * 4 + 2] = fmaf(w, f.z, acc[q * 4 + 2]);
                acc[q * 4 + 3] = fmaf(w, f.w, acc[q * 4 + 3]);
            }
        }
    }
    const int ii = n >> 4, jj = n & 15;
    float* ob = out + ((size_t)b * CIN + c0) * PLANE + (size_t)(gI * 16 * HH + gJ * 16) + ii * HH + jj;
#pragma unroll
    for (int cc = 0; cc < 16; ++cc) ob[(size_t)cc * PLANE] = acc[cc];
}

extern "C" void kernel_launch(void* const* d_in, const int* in_sizes, int n_in,
                              void* d_out, int out_size, void* d_ws, size_t ws_size,
                              hipStream_t stream) {
    const float* x  = (const float*)d_in[0];
    const float* fw = (const float*)d_in[1];
    const float* fb = (const float*)d_in[2];
    const float* ea = (const float*)d_in[3];
    const float* eb = (const float*)d_in[4];
    float* out = (float*)d_out;

    int nB = in_sizes[0] / (CIN * PLANE);   // 4
    int nP = nB * 49;                       // 196
    size_t nRows = (size_t)nP * NN;         // 50176

    char* wsb = (char*)d_ws;
    size_t off = 0;
    auto carve = [&](size_t bytes) { char* r = wsb + off; off = (off + bytes + 255) & ~(size_t)255; return r; };
    double*   xa64   = (double*)  carve(nRows * ROWSTRIDE * sizeof(double));
    float*    xa32   = (float*)   carve(nRows * ROWSTRIDE * sizeof(float));
    int*      topi   = (int*)     carve(nRows * 16 * sizeof(int));
    float*    wk     = (float*)   carve(nRows * 16 * sizeof(float));
    unsigned* dcnt   = (unsigned*)carve(256);
    int*      dlist  = (int*)     carve(nRows * sizeof(int));

    hipLaunchKernelGGL(k1_features, dim3(nP * 4), dim3(256), 0, stream, x, fw, fb, xa64, xa32, dcnt);
    hipLaunchKernelGGL(k2_select,   dim3(nP * 16), dim3(256), 0, stream, xa32, ea, eb, topi, wk, dcnt, dlist);
    hipLaunchKernelGGL(k2b_dirty,   dim3(256), dim3(64), 0, stream, xa64, ea, eb, dcnt, dlist, topi, wk);
    hipLaunchKernelGGL(k3_aggregate, dim3(nP * 8), dim3(256), 0, stream, x, topi, wk, out);
}